// Round 5
// baseline (202.300 us; speedup 1.0000x reference)
//
#include <hip/hip_runtime.h>

#define NPTS     65536
#define BATCHES  16
#define CHANNELS 256
#define LOUT     8192
#define TJ       512                  // j-extent per block -> 2KB write runs
#define CGRP     32                   // channels per block (row chunk = 128B = 1 L2 line)
#define NTILES   (LOUT / TJ)          // 16 j-tiles
#define NCG      (CHANNELS / CGRP)    // 8 channel groups
#define MAX_ROWS 288                  // 288*33*4 = 38 KB LDS -> 4 blocks/CU
#define STRIDE   (CGRP + 1)           // 33: gather bank = (row+c) mod 32, 2-way max

typedef float f32x2 __attribute__((ext_vector_type(2)));  // nt-store-compatible

// Block = (batch b, channel-group cg, j-tile). blockIdx = b*128 + cg*16 + jt:
// since 16 % 8 == 0, all 8 cg-blocks of one (b,jt) land on the same XCD ->
// their complementary 128B row slices are L2-local. Stage rows [s0..s1] x 32
// channels into padded LDS (coalesced float4), then transpose-gather: waves
// own channel residues, lanes own j-pairs over 4 passes -> 512B nt-stores
// composing 2KB contiguous runs per channel row.
__global__ __launch_bounds__(256, 4) void k_main(
    const float* __restrict__ px,    // [N,3]
    const float* __restrict__ pf,    // [N,C]
    const int*   __restrict__ batch, // [N], sorted batch ids
    float*       __restrict__ out)   // [B*3*L] then [B*C*L]
{
    __shared__ float tile[MAX_ROWS * STRIDE];
    __shared__ int   sb[2];

    const int t    = threadIdx.x;
    const int lane = t & 63;
    const int wv   = t >> 6;
    const int jt   = blockIdx.x & (NTILES - 1);
    const int cg   = (blockIdx.x >> 4) & (NCG - 1);
    const int b    = blockIdx.x >> 7;
    const int j0   = jt * TJ;

    // threads 0,1: lower_bound(batch, b + t)   (L2-hot after first blocks)
    if (t < 2) {
        const int target = b + t;
        int lo = 0;
        if (target >= BATCHES) {
            lo = NPTS;
        } else {
            int hi = NPTS;
            while (lo < hi) {
                const int mid = (lo + hi) >> 1;
                if (batch[mid] < target) lo = mid + 1; else hi = mid;
            }
        }
        sb[t] = lo;
    }
    __syncthreads();
    const int offs = sb[0];
    const int cnt  = sb[1] - sb[0];

    // output index j -> global source row (clamped like JAX OOB gather)
    auto srow = [&](int j) -> int {
        const int s = offs + ((j * cnt) >> 13);   // L = 8192 = 2^13
        return s < (NPTS - 1) ? s : (NPTS - 1);
    };

    const int s0 = srow(j0);
    const int s1 = srow(j0 + TJ - 1);
    const int R  = s1 - s0 + 1;

    // per-lane j-pair source rows, four passes k = 0..3 (128 j per pass)
    int gA[4], gB[4];
    #pragma unroll
    for (int k = 0; k < 4; ++k) {
        const int j = j0 + 2 * lane + 128 * k;
        gA[k] = srow(j);
        gB[k] = srow(j + 1);
    }

    float* outf = out + (size_t)BATCHES * 3 * LOUT;   // feature section
    float* opBase = outf + ((size_t)(b * CHANNELS + cg * CGRP)) * LOUT + j0 + 2 * lane;

    if (R <= MAX_ROWS) {
        // ---- stage rows [s0,s1] x this channel group into LDS ----
        const float4* in4 = (const float4*)(pf + (size_t)s0 * CHANNELS + cg * CGRP);
        const int n4 = R * (CGRP / 4);            // 8 float4 per row
        for (int e = t; e < n4; e += 256) {
            const int row = e >> 3;
            const int c4  = e & 7;
            const float4 v = in4[row * (CHANNELS / 4) + c4];
            float* dst = &tile[row * STRIDE + c4 * 4];
            dst[0] = v.x; dst[1] = v.y; dst[2] = v.z; dst[3] = v.w;
        }
        __syncthreads();

        int la[4], lb[4];
        #pragma unroll
        for (int k = 0; k < 4; ++k) {
            la[k] = (gA[k] - s0) * STRIDE;
            lb[k] = (gB[k] - s0) * STRIDE;
        }
        #pragma unroll 2
        for (int c = wv; c < CGRP; c += 4) {
            float* op = opBase + (size_t)c * LOUT;
            #pragma unroll
            for (int k = 0; k < 4; ++k) {
                f32x2 v;
                v.x = tile[la[k] + c];
                v.y = tile[lb[k] + c];
                __builtin_nontemporal_store(v, (f32x2*)(op + 128 * k));
            }
        }
    } else {
        // ---- fallback (pathologically skewed batch): direct gather ----
        for (int c = wv; c < CGRP; c += 4) {
            float* op = opBase + (size_t)c * LOUT;
            const int cc = cg * CGRP + c;
            #pragma unroll
            for (int k = 0; k < 4; ++k) {
                f32x2 v;
                v.x = pf[(size_t)gA[k] * CHANNELS + cc];
                v.y = pf[(size_t)gB[k] * CHANNELS + cc];
                __builtin_nontemporal_store(v, (f32x2*)(op + 128 * k));
            }
        }
    }

    // ---- out_point: only cg==0 blocks, waves 0..2 handle coord d = wv ----
    if (cg == 0 && wv < 3) {
        #pragma unroll
        for (int k = 0; k < 4; ++k) {
            f32x2 v;
            v.x = px[gA[k] * 3 + wv];
            v.y = px[gB[k] * 3 + wv];
            __builtin_nontemporal_store(
                v, (f32x2*)(out + ((size_t)(b * 3 + wv)) * LOUT + j0 + 2 * lane + 128 * k));
        }
    }
}

extern "C" void kernel_launch(void* const* d_in, const int* in_sizes, int n_in,
                              void* d_out, int out_size, void* d_ws, size_t ws_size,
                              hipStream_t stream) {
    const float* px    = (const float*)d_in[0];   // points_x [N,3]
    const float* pf    = (const float*)d_in[1];   // point_features [N,C]
    const int*   batch = (const int*)d_in[2];     // batch ids [N], sorted
    float* out = (float*)d_out;

    k_main<<<BATCHES * NCG * NTILES, 256, 0, stream>>>(px, pf, batch, out);
}